// Round 19
// baseline (459.588 us; speedup 1.0000x reference)
//
#include <hip/hip_runtime.h>
#include <hip/hip_bf16.h>

#define D 128
#define N_TAXON 100000
#define N_SOTU 200000
#define N_ALL 300000
#define E_HP 200000
#define E_RH 2000000
#define E_ALL 2200000
#define OUTC 64
#define NBUCK 147     // ceil(300000 / 2048)
#define BSHIFT 11
#define BCAP 24576    // fixed bucket capacity (rh mean 20480, +28 sigma)

typedef __hip_bfloat16 bf16;
typedef __bf16 bf16v8 __attribute__((ext_vector_type(8)));
typedef float f32x4 __attribute__((ext_vector_type(4)));
typedef int i32x4 __attribute__((ext_vector_type(4)));
typedef unsigned u32x2 __attribute__((ext_vector_type(2)));

union Frag { i32x4 i; bf16v8 v; };

__device__ __forceinline__ float bflo(unsigned u) { return __uint_as_float(u << 16); }
__device__ __forceinline__ float bfhi(unsigned u) { return __uint_as_float(u & 0xffff0000u); }

__device__ __forceinline__ unsigned short f2bf(float x) {
    unsigned u = __float_as_uint(x);
    unsigned r = (u + 0x7fffu + ((u >> 16) & 1u)) >> 16;   // round-to-nearest-even
    return (unsigned short)r;
}
__device__ __forceinline__ unsigned packbf(float a, float b) {
    return (unsigned)f2bf(a) | ((unsigned)f2bf(b) << 16);
}

// ---------------- partition all edges into fixed-capacity global-dst buckets ----------------
// ebuf entry: (dloc << 17) | src   (dloc < 2048, src < 131072)
__global__ __launch_bounds__(256) void partition_kernel(
    const int* __restrict__ hp_src, const int* __restrict__ hp_dst,
    const int* __restrict__ rh_src, const int* __restrict__ rh_dst,
    unsigned* __restrict__ bcnt, unsigned* __restrict__ ebuf)
{
    __shared__ unsigned hist[NBUCK];
    __shared__ unsigned lcur[NBUCK];
    int base = blockIdx.x * 4096;
    for (int i = threadIdx.x; i < NBUCK; i += 256) hist[i] = 0;
    __syncthreads();
    int s[16], d[16];
#pragma unroll
    for (int k = 0; k < 16; ++k) {
        int e = base + k * 256 + threadIdx.x;
        if (e < E_HP) {
            s[k] = hp_src[e]; d[k] = hp_dst[e];
            atomicAdd(&hist[d[k] >> BSHIFT], 1u);
        } else if (e < E_ALL) {
            s[k] = rh_src[e - E_HP]; d[k] = N_TAXON + rh_dst[e - E_HP];
            atomicAdd(&hist[d[k] >> BSHIFT], 1u);
        } else d[k] = -1;
    }
    __syncthreads();
    for (int i = threadIdx.x; i < NBUCK; i += 256)
        lcur[i] = atomicAdd(&bcnt[i], hist[i]);
    __syncthreads();
#pragma unroll
    for (int k = 0; k < 16; ++k) {
        if (d[k] >= 0) {
            int c = d[k] >> BSHIFT;
            unsigned slot = atomicAdd(&lcur[c], 1u);
            ebuf[(unsigned)c * BCAP + slot] =
                ((unsigned)(d[k] & ((1 << BSHIFT) - 1)) << 17) | (unsigned)s[k];
        }
    }
}

// ---------------- bucket prefix from actual counts (+ row_ptr sentinel) ----------------
__global__ __launch_bounds__(256) void scan147_kernel(const unsigned* __restrict__ bcnt,
                                                      unsigned* __restrict__ bstart,
                                                      unsigned* __restrict__ row_ptr)
{
    if (threadIdx.x == 0) {
        unsigned acc = 0;
        for (int b = 0; b < NBUCK; ++b) { bstart[b] = acc; acc += bcnt[b]; }
        bstart[NBUCK] = acc;
        row_ptr[N_ALL] = E_ALL;   // sentinel
    }
}

// ---------------- per-bucket: LDS count + scan -> row_ptr + dense fill ----------------
__global__ __launch_bounds__(256) void fillB_kernel(const unsigned* __restrict__ ebuf,
                                                    const unsigned* __restrict__ bcnt,
                                                    const unsigned* __restrict__ bstart,
                                                    unsigned* __restrict__ row_ptr,
                                                    int* __restrict__ sorted_all)
{
    __shared__ unsigned hist[1 << BSHIFT];   // 8KB: counts -> absolute cursors
    __shared__ unsigned wsum[4];
    int c = blockIdx.x;
    int dbase = c << BSHIFT;
    for (int i = threadIdx.x; i < (1 << BSHIFT); i += 256) hist[i] = 0;
    __syncthreads();
    const unsigned* eb = ebuf + (unsigned)c * BCAP;
    unsigned n = bcnt[c];
    for (unsigned e = threadIdx.x; e < n; e += 256)
        atomicAdd(&hist[eb[e] >> 17], 1u);
    __syncthreads();
    int base8 = threadIdx.x * 8;
    unsigned loc[8], s = 0;
#pragma unroll
    for (int i = 0; i < 8; ++i) { loc[i] = s; s += hist[base8 + i]; }
    int lane = threadIdx.x & 63, wv = threadIdx.x >> 6;
    unsigned sc = s;
    for (int off = 1; off < 64; off <<= 1) {
        unsigned t = __shfl_up(sc, off, 64);
        if (lane >= off) sc += t;
    }
    if (lane == 63) wsum[wv] = sc;
    __syncthreads();
    unsigned woff = 0;
    for (int w = 0; w < wv; ++w) woff += wsum[w];
    unsigned tbase = bstart[c] + woff + sc - s;   // absolute exclusive prefix
#pragma unroll
    for (int i = 0; i < 8; ++i) {
        int dd = dbase + base8 + i;
        unsigned p = tbase + loc[i];
        if (dd < N_ALL) row_ptr[dd] = p;
        hist[base8 + i] = p;                      // becomes the fill cursor
    }
    __syncthreads();
    for (unsigned e = threadIdx.x; e < n; e += 256) {
        unsigned v = eb[e];
        unsigned pos = atomicAdd(&hist[v >> 17], 1u);
        sorted_all[pos] = (int)(v & 0x1FFFFu);
    }
}

// ---------------- all weights: transpose + bf16 + XOR-swizzle ----------------
__global__ __launch_bounds__(256) void wprep_all_kernel(
    const float* __restrict__ W1l, const float* __restrict__ W1r,
    const float* __restrict__ W2l, const float* __restrict__ W2r,
    const float* __restrict__ W3l, const float* __restrict__ W3r,
    const float* __restrict__ Wlin, unsigned short* __restrict__ wtbase)
{
    int e = blockIdx.x * 256 + threadIdx.x;
    if (e >= 6 * 16384 + 8192) return;
    const float* srcs[7] = { W1l, W1r, W2l, W2r, W3l, W3r, Wlin };
    int m = e >> 14;
    int local = (m < 6) ? (e & 16383) : (e - 98304);
    int N = (m < 6) ? 128 : 64;
    int k = local / N, col = local - k * N;
    unsigned short* dst = wtbase + ((m < 6) ? m * 16384 : 98304);
    dst[(col * 128 + k) ^ ((col & 7) << 3)] = f2bf(srcs[m][local]);
}

// ---------------- gemmTh2: fused hp-mean gather + dual GEMM -> full X2 rows ----------------
__global__ __launch_bounds__(1024) void gemmTh2_kernel(
    const float* __restrict__ X /*x_taxon f32*/,
    const unsigned* __restrict__ rp, const int* __restrict__ nbr,
    const unsigned short* __restrict__ WtA, const unsigned short* __restrict__ WtB,
    const float* __restrict__ bias, unsigned* __restrict__ X2, int M)
{
    __shared__ char sW[65536];
    __shared__ unsigned tiles[16 * 1024];
    int tid = threadIdx.x;
    int wave = tid >> 6, lane = tid & 63;
    int ln = lane & 15, g = lane >> 4;
    int rbase = blockIdx.x * 256 + wave * 16;
    unsigned* tile = tiles + wave * 1024;

    // preload + pack own x-row early (overlaps weight staging and gather)
    int row = rbase + ln;
    int rl = row < M ? row : M - 1;
    const f32x4* xr = (const f32x4*)(X + (size_t)rl * 128);
    i32x4 xpk[4];
#pragma unroll
    for (int ks = 0; ks < 4; ++ks) {
        f32x4 fa = xr[ks * 8 + g * 2], fb = xr[ks * 8 + g * 2 + 1];
        i32x4 t = { (int)packbf(fa.x, fa.y), (int)packbf(fa.z, fa.w),
                    (int)packbf(fb.x, fb.y), (int)packbf(fb.z, fb.w) };
        xpk[ks] = t;
    }

    ((i32x4*)sW)[tid]        = ((const i32x4*)WtA)[tid];
    ((i32x4*)sW)[tid + 1024] = ((const i32x4*)WtA)[tid + 1024];
    ((i32x4*)sW)[tid + 2048] = ((const i32x4*)WtB)[tid];
    ((i32x4*)sW)[tid + 3072] = ((const i32x4*)WtB)[tid + 1024];

    // gather phase: mean of hp neighbors for the wave's 16 rows (deg~2)
    for (int i = 0; i < 16; ++i) {
        int r = rbase + i;
        float a0 = 0.f, a1 = 0.f;
        if (r < M) {
            unsigned beg = rp[r], end = rp[r + 1];
            unsigned u = beg;
            for (; u + 2 <= end; u += 2) {
                float2 A = ((const float2*)X)[(size_t)nbr[u] * 64 + lane];
                float2 B = ((const float2*)X)[(size_t)nbr[u + 1] * 64 + lane];
                a0 += A.x + B.x; a1 += A.y + B.y;
            }
            if (u < end) {
                float2 A = ((const float2*)X)[(size_t)nbr[u] * 64 + lane];
                a0 += A.x; a1 += A.y;
            }
            unsigned cdeg = end - beg;
            float inv = 1.f / (float)(cdeg ? cdeg : 1u);
            a0 *= inv; a1 *= inv;
        }
        tile[i * 64 + (lane ^ ((i & 7) << 2))] = packbf(a0, a1);
    }
    __syncthreads();

    // GEMM phase
    int swzW = (ln & 7) << 4;
    int swz = (ln & 7) << 2;

    f32x4 acc[8];
#pragma unroll
    for (int cf = 0; cf < 8; ++cf) acc[cf] = ((const f32x4*)bias)[cf * 4 + g];

    unsigned* orow = X2 + (size_t)row * 128;
#pragma unroll
    for (int ks = 0; ks < 4; ++ks) {
        Frag mf; mf.i = *(const i32x4*)&tile[ln * 64 + ((ks * 16 + g * 4) ^ swz)];
        Frag xf; xf.i = xpk[ks];
#pragma unroll
        for (int cf = 0; cf < 8; ++cf) {
            int off = (((cf * 16 + ln) << 8) + (ks << 6) + (g << 4)) ^ swzW;
            Frag wa; wa.i = *(const i32x4*)(sW + off);
            Frag wb; wb.i = *(const i32x4*)(sW + 32768 + off);
            acc[cf] = __builtin_amdgcn_mfma_f32_16x16x32_bf16(wa.v, mf.v, acc[cf], 0, 0, 0);
            acc[cf] = __builtin_amdgcn_mfma_f32_16x16x32_bf16(wb.v, xf.v, acc[cf], 0, 0, 0);
        }
    }

    if (row < M) {
#pragma unroll
        for (int ks = 0; ks < 4; ++ks) {
            int p0 = 16 * ks + 4 * g;
            orow[(p0 + 0) * 2] = (unsigned)xpk[ks][0];
            orow[(p0 + 1) * 2] = (unsigned)xpk[ks][1];
            orow[(p0 + 2) * 2] = (unsigned)xpk[ks][2];
            orow[(p0 + 3) * 2] = (unsigned)xpk[ks][3];
        }
#pragma unroll
        for (int cf = 0; cf < 8; ++cf) {
            int p = cf * 8 + g * 2;
            orow[p * 2 + 1]       = packbf(fmaxf(acc[cf][0], 0.f), fmaxf(acc[cf][1], 0.f));
            orow[(p + 1) * 2 + 1] = packbf(fmaxf(acc[cf][2], 0.f), fmaxf(acc[cf][3], 0.f));
        }
    }
}

// ---------------- merged rh gather: chunk-16 MLP, XCD-swizzled ----------------
__global__ __launch_bounds__(256) void aggMean2_kernel(
    const unsigned* __restrict__ X2, const unsigned* __restrict__ rp,
    const int* __restrict__ nbr,
    unsigned* __restrict__ meanXrh, unsigned* __restrict__ meanH)
{
    int wave = threadIdx.x >> 6, lane = threadIdx.x & 63;
    int bid = (blockIdx.x & 7) * 6250 + (blockIdx.x >> 3);   // grid = 50000
    int r = bid * 4 + wave;
    unsigned beg = rp[r], end = rp[r + 1];
    float a0 = 0.f, a1 = 0.f, a2 = 0.f, a3 = 0.f;
    unsigned u = beg;
    for (; u + 16 <= end; u += 16) {
        int j[16];
#pragma unroll
        for (int k = 0; k < 16; ++k) j[k] = nbr[u + k];
        u32x2 A[16];
#pragma unroll
        for (int k = 0; k < 16; ++k)
            A[k] = *(const u32x2*)(X2 + (size_t)j[k] * 128 + lane * 2);
#pragma unroll
        for (int k = 0; k < 16; ++k) {
            a0 += bflo(A[k].x); a1 += bfhi(A[k].x);
            a2 += bflo(A[k].y); a3 += bfhi(A[k].y);
        }
    }
    for (; u + 4 <= end; u += 4) {
        int j[4];
#pragma unroll
        for (int k = 0; k < 4; ++k) j[k] = nbr[u + k];
        u32x2 A[4];
#pragma unroll
        for (int k = 0; k < 4; ++k)
            A[k] = *(const u32x2*)(X2 + (size_t)j[k] * 128 + lane * 2);
#pragma unroll
        for (int k = 0; k < 4; ++k) {
            a0 += bflo(A[k].x); a1 += bfhi(A[k].x);
            a2 += bflo(A[k].y); a3 += bfhi(A[k].y);
        }
    }
    for (; u < end; ++u) {
        u32x2 A = *(const u32x2*)(X2 + (size_t)nbr[u] * 128 + lane * 2);
        a0 += bflo(A.x); a1 += bfhi(A.x); a2 += bflo(A.y); a3 += bfhi(A.y);
    }
    unsigned c = end - beg;
    float inv = 1.f / (float)(c ? c : 1u);
    meanXrh[(size_t)r * 64 + lane] = packbf(a0 * inv, a1 * inv);
    meanH[(size_t)r * 64 + lane]   = packbf(a2 * inv, a3 * inv);
}

// ---------------- megaTail: sotu_h (LDS tiles) -> h2 (in-place) -> out ----------------
__global__ __launch_bounds__(1024) void megaTail_kernel(
    const unsigned* __restrict__ meanXrh, const float* __restrict__ xs,
    const unsigned* __restrict__ meanH,
    const unsigned short* __restrict__ Wt2l, const unsigned short* __restrict__ Wt2r,
    const unsigned short* __restrict__ Wt3l, const unsigned short* __restrict__ Wt3r,
    const unsigned short* __restrict__ Wtlin,
    const float* __restrict__ b2, const float* __restrict__ b3,
    const float* __restrict__ blin, float* __restrict__ out, int M)
{
    __shared__ char sW[65536];
    __shared__ unsigned tiles[16 * 1024];
    int tid = threadIdx.x;
    int wave = tid >> 6, lane = tid & 63;
    int ln = lane & 15, g = lane >> 4;
    int row = blockIdx.x * 256 + wave * 16 + ln;
    int rl = row < M ? row : M - 1;
    int swzW = (ln & 7) << 4;
    int swz = (ln & 7) << 2;
    unsigned* tile = tiles + wave * 1024;

    // ---- preload ALL per-row inputs early (overlap with weight staging) ----
    i32x4 mfp[4], mh[4], xpk[4];
    {
        const i32x4* a1r = (const i32x4*)(meanXrh + (size_t)rl * 64);
        const i32x4* hr  = (const i32x4*)(meanH + (size_t)rl * 64);
        const f32x4* xr  = (const f32x4*)(xs + (size_t)rl * 128);
#pragma unroll
        for (int ks = 0; ks < 4; ++ks) {
            mfp[ks] = a1r[ks * 4 + g];
            mh[ks]  = hr[ks * 4 + g];
            f32x4 fa = xr[ks * 8 + g * 2], fb = xr[ks * 8 + g * 2 + 1];
            i32x4 t = { (int)packbf(fa.x, fa.y), (int)packbf(fa.z, fa.w),
                        (int)packbf(fb.x, fb.y), (int)packbf(fb.z, fb.w) };
            xpk[ks] = t;
        }
    }

    i32x4 w3pre[4], wlpre;
    w3pre[0] = ((const i32x4*)Wt3l)[tid];
    w3pre[1] = ((const i32x4*)Wt3l)[tid + 1024];
    w3pre[2] = ((const i32x4*)Wt3r)[tid];
    w3pre[3] = ((const i32x4*)Wt3r)[tid + 1024];
    wlpre    = ((const i32x4*)Wtlin)[tid];

    ((i32x4*)sW)[tid]        = ((const i32x4*)Wt2l)[tid];
    ((i32x4*)sW)[tid + 1024] = ((const i32x4*)Wt2l)[tid + 1024];
    ((i32x4*)sW)[tid + 2048] = ((const i32x4*)Wt2r)[tid];
    ((i32x4*)sW)[tid + 3072] = ((const i32x4*)Wt2r)[tid + 1024];
    __syncthreads();   // B1

    // phase A: sotu_h = relu(meanXrh@W2l + x_sotu@W2r + b2) -> tile
    {
        f32x4 acc[8];
#pragma unroll
        for (int cf = 0; cf < 8; ++cf) acc[cf] = ((const f32x4*)b2)[cf * 4 + g];
#pragma unroll
        for (int ks = 0; ks < 4; ++ks) {
            Frag mf; mf.i = mfp[ks];
            Frag xf; xf.i = xpk[ks];
#pragma unroll
            for (int cf = 0; cf < 8; ++cf) {
                int off = (((cf * 16 + ln) << 8) + (ks << 6) + (g << 4)) ^ swzW;
                Frag wa; wa.i = *(const i32x4*)(sW + off);
                Frag wb; wb.i = *(const i32x4*)(sW + 32768 + off);
                acc[cf] = __builtin_amdgcn_mfma_f32_16x16x32_bf16(wa.v, mf.v, acc[cf], 0, 0, 0);
                acc[cf] = __builtin_amdgcn_mfma_f32_16x16x32_bf16(wb.v, xf.v, acc[cf], 0, 0, 0);
            }
        }
#pragma unroll
        for (int cf = 0; cf < 8; ++cf) {
            u32x2 o;
            o.x = packbf(fmaxf(acc[cf][0], 0.f), fmaxf(acc[cf][1], 0.f));
            o.y = packbf(fmaxf(acc[cf][2], 0.f), fmaxf(acc[cf][3], 0.f));
            *(u32x2*)&tile[ln * 64 + ((cf * 8 + g * 2) ^ swz)] = o;
        }
    }
    __syncthreads();   // B2
    ((i32x4*)sW)[tid]        = w3pre[0];
    ((i32x4*)sW)[tid + 1024] = w3pre[1];
    ((i32x4*)sW)[tid + 2048] = w3pre[2];
    ((i32x4*)sW)[tid + 3072] = w3pre[3];
    __syncthreads();   // B3

    // phase B: h2 = relu(meanH@W3l + sotu_h@W3r + b3) -> tile (in place)
    {
        f32x4 acc2[8];
#pragma unroll
        for (int cf = 0; cf < 8; ++cf) acc2[cf] = ((const f32x4*)b3)[cf * 4 + g];
#pragma unroll
        for (int ks = 0; ks < 4; ++ks) {
            Frag mf; mf.i = mh[ks];
            Frag sf; sf.i = *(const i32x4*)&tile[ln * 64 + ((ks * 16 + g * 4) ^ swz)];
#pragma unroll
            for (int cf = 0; cf < 8; ++cf) {
                int off = (((cf * 16 + ln) << 8) + (ks << 6) + (g << 4)) ^ swzW;
                Frag wl; wl.i = *(const i32x4*)(sW + off);
                Frag wr; wr.i = *(const i32x4*)(sW + 32768 + off);
                acc2[cf] = __builtin_amdgcn_mfma_f32_16x16x32_bf16(wl.v, mf.v, acc2[cf], 0, 0, 0);
                acc2[cf] = __builtin_amdgcn_mfma_f32_16x16x32_bf16(wr.v, sf.v, acc2[cf], 0, 0, 0);
            }
        }
#pragma unroll
        for (int cf = 0; cf < 8; ++cf) {
            u32x2 o;
            o.x = packbf(fmaxf(acc2[cf][0], 0.f), fmaxf(acc2[cf][1], 0.f));
            o.y = packbf(fmaxf(acc2[cf][2], 0.f), fmaxf(acc2[cf][3], 0.f));
            *(u32x2*)&tile[ln * 64 + ((cf * 8 + g * 2) ^ swz)] = o;
        }
    }
    __syncthreads();   // B4
    ((i32x4*)sW)[tid] = wlpre;
    __syncthreads();   // B5

    // phase C: out = h2 @ Wlin + blin
    f32x4 aL[4];
#pragma unroll
    for (int cf = 0; cf < 4; ++cf) aL[cf] = ((const f32x4*)blin)[cf * 4 + g];
#pragma unroll
    for (int ks = 0; ks < 4; ++ks) {
        Frag hf; hf.i = *(const i32x4*)&tile[ln * 64 + ((ks * 16 + g * 4) ^ swz)];
#pragma unroll
        for (int cf = 0; cf < 4; ++cf) {
            int off = (((cf * 16 + ln) << 8) + (ks << 6) + (g << 4)) ^ swzW;
            Frag wf; wf.i = *(const i32x4*)(sW + off);
            aL[cf] = __builtin_amdgcn_mfma_f32_16x16x32_bf16(wf.v, hf.v, aL[cf], 0, 0, 0);
        }
    }
    if (row < M) {
        float* orow = out + (size_t)row * OUTC;
#pragma unroll
        for (int cf = 0; cf < 4; ++cf)
            *(f32x4*)(orow + cf * 16 + g * 4) = aL[cf];
    }
}

extern "C" void kernel_launch(void* const* d_in, const int* in_sizes, int n_in,
                              void* d_out, int out_size, void* d_ws, size_t ws_size,
                              hipStream_t stream)
{
    const float* x_taxon = (const float*)d_in[0];
    const float* x_sotu  = (const float*)d_in[1];
    const int* hp_src = (const int*)d_in[2];
    const int* hp_dst = (const int*)d_in[3];
    const int* rh_src = (const int*)d_in[4];
    const int* rh_dst = (const int*)d_in[5];
    const float* W1l = (const float*)d_in[6];
    const float* W1r = (const float*)d_in[7];
    const float* b1  = (const float*)d_in[8];
    const float* W2l = (const float*)d_in[9];
    const float* W2r = (const float*)d_in[10];
    const float* b2  = (const float*)d_in[11];
    const float* W3l = (const float*)d_in[12];
    const float* W3r = (const float*)d_in[13];
    const float* b3  = (const float*)d_in[14];
    const float* Wlin = (const float*)d_in[15];
    const float* blin = (const float*)d_in[16];
    float* out = (float*)d_out;

    // ---- workspace layout (bytes) ----
    char* ws = (char*)d_ws;
    unsigned* X2      = (unsigned*)(ws);                  // [100K][128] xt|taxon_h interleaved
    unsigned* meanXrh = (unsigned*)(ws + 51200000);       // [200K][64]; ebuf overlays (dead first)
    unsigned* meanH   = (unsigned*)(ws + 102400000);      // [200K][64]
    unsigned* ebuf    = (unsigned*)(ws + 51200000);       // [147*24576] u32 = 14.5MB, dead before aggMean2
    int*      sorted_all = (int*)(ws + 179200000);        // [E_ALL] 8.8MB
    unsigned* row_ptr = (unsigned*)(ws + 188000000);      // [300001]
    unsigned* bcnt    = (unsigned*)(ws + 189200128);      // [160]
    unsigned* bstart  = (unsigned*)(ws + 189200768);      // [160]
    unsigned short* wtbase = (unsigned short*)(ws + 189201408);
    unsigned short* Wt1l = wtbase;
    unsigned short* Wt1r = wtbase + 16384;
    unsigned short* Wt2l = wtbase + 32768;
    unsigned short* Wt2r = wtbase + 49152;
    unsigned short* Wt3l = wtbase + 65536;
    unsigned short* Wt3r = wtbase + 81920;
    unsigned short* Wtlin = wtbase + 98304;

    // zero bcnt only
    hipMemsetAsync(bcnt, 0, 640, stream);

    // ---- weight prep (independent) ----
    wprep_all_kernel<<<(6 * 16384 + 8192 + 255) / 256, 256, 0, stream>>>(
        W1l, W1r, W2l, W2r, W3l, W3r, Wlin, wtbase);

    // ---- unified CSR build (fixed-capacity buckets, no count pass) ----
    partition_kernel<<<(E_ALL + 4095) / 4096, 256, 0, stream>>>(
        hp_src, hp_dst, rh_src, rh_dst, bcnt, ebuf);
    scan147_kernel<<<1, 256, 0, stream>>>(bcnt, bstart, row_ptr);
    fillB_kernel<<<NBUCK, 256, 0, stream>>>(ebuf, bcnt, bstart, row_ptr, sorted_all);

    // ---- fused hp-mean + taxon_h GEMM -> full X2 rows ----
    gemmTh2_kernel<<<(N_TAXON + 255) / 256, 1024, 0, stream>>>(
        x_taxon, row_ptr, sorted_all, Wt1l, Wt1r, b1, X2, N_TAXON);

    // ---- merged rh gather: meanXrh + meanH in one walk (chunk-16) ----
    aggMean2_kernel<<<N_SOTU / 4, 256, 0, stream>>>(
        X2, row_ptr + N_TAXON, sorted_all, meanXrh, meanH);

    // ---- megaTail: sotu_h -> h2 (LDS) -> out ----
    megaTail_kernel<<<(N_SOTU + 255) / 256, 1024, 0, stream>>>(
        meanXrh, x_sotu, meanH, Wt2l, Wt2r, Wt3l, Wt3r, Wtlin, b2, b3, blin, out, N_SOTU);
}

// Round 20
// 414.518 us; speedup vs baseline: 1.1087x; 1.1087x over previous
//
#include <hip/hip_runtime.h>
#include <hip/hip_bf16.h>

#define D 128
#define N_TAXON 100000
#define N_SOTU 200000
#define N_ALL 300000
#define E_HP 200000
#define E_RH 2000000
#define E_ALL 2200000
#define OUTC 64
#define NBUCK 147     // ceil(300000 / 2048)
#define BSHIFT 11
#define BCAP 24576    // fixed bucket capacity (rh mean 20480, +28 sigma)

typedef __hip_bfloat16 bf16;
typedef __bf16 bf16v8 __attribute__((ext_vector_type(8)));
typedef float f32x4 __attribute__((ext_vector_type(4)));
typedef int i32x4 __attribute__((ext_vector_type(4)));
typedef unsigned u32x2 __attribute__((ext_vector_type(2)));

union Frag { i32x4 i; bf16v8 v; };

__device__ __forceinline__ float bflo(unsigned u) { return __uint_as_float(u << 16); }
__device__ __forceinline__ float bfhi(unsigned u) { return __uint_as_float(u & 0xffff0000u); }

__device__ __forceinline__ unsigned short f2bf(float x) {
    unsigned u = __float_as_uint(x);
    unsigned r = (u + 0x7fffu + ((u >> 16) & 1u)) >> 16;   // round-to-nearest-even
    return (unsigned short)r;
}
__device__ __forceinline__ unsigned packbf(float a, float b) {
    return (unsigned)f2bf(a) | ((unsigned)f2bf(b) << 16);
}

// ---------------- partition all edges into fixed-capacity global-dst buckets ----------------
// ebuf entry: (dloc << 17) | src   (dloc < 2048, src < 131072)
__global__ __launch_bounds__(256) void partition_kernel(
    const int* __restrict__ hp_src, const int* __restrict__ hp_dst,
    const int* __restrict__ rh_src, const int* __restrict__ rh_dst,
    unsigned* __restrict__ bcnt, unsigned* __restrict__ ebuf)
{
    __shared__ unsigned hist[NBUCK];
    __shared__ unsigned lcur[NBUCK];
    int base = blockIdx.x * 4096;
    for (int i = threadIdx.x; i < NBUCK; i += 256) hist[i] = 0;
    __syncthreads();
    int s[16], d[16];
#pragma unroll
    for (int k = 0; k < 16; ++k) {
        int e = base + k * 256 + threadIdx.x;
        if (e < E_HP) {
            s[k] = hp_src[e]; d[k] = hp_dst[e];
            atomicAdd(&hist[d[k] >> BSHIFT], 1u);
        } else if (e < E_ALL) {
            s[k] = rh_src[e - E_HP]; d[k] = N_TAXON + rh_dst[e - E_HP];
            atomicAdd(&hist[d[k] >> BSHIFT], 1u);
        } else d[k] = -1;
    }
    __syncthreads();
    for (int i = threadIdx.x; i < NBUCK; i += 256)
        lcur[i] = atomicAdd(&bcnt[i], hist[i]);
    __syncthreads();
#pragma unroll
    for (int k = 0; k < 16; ++k) {
        if (d[k] >= 0) {
            int c = d[k] >> BSHIFT;
            unsigned slot = atomicAdd(&lcur[c], 1u);
            ebuf[(unsigned)c * BCAP + slot] =
                ((unsigned)(d[k] & ((1 << BSHIFT) - 1)) << 17) | (unsigned)s[k];
        }
    }
}

// ---------------- bucket prefix from actual counts (+ row_ptr sentinel) ----------------
__global__ __launch_bounds__(256) void scan147_kernel(const unsigned* __restrict__ bcnt,
                                                      unsigned* __restrict__ bstart,
                                                      unsigned* __restrict__ row_ptr)
{
    if (threadIdx.x == 0) {
        unsigned acc = 0;
        for (int b = 0; b < NBUCK; ++b) { bstart[b] = acc; acc += bcnt[b]; }
        bstart[NBUCK] = acc;
        row_ptr[N_ALL] = E_ALL;   // sentinel
    }
}

// ---------------- per-bucket: LDS count + scan -> row_ptr + dense fill ----------------
__global__ __launch_bounds__(256) void fillB_kernel(const unsigned* __restrict__ ebuf,
                                                    const unsigned* __restrict__ bcnt,
                                                    const unsigned* __restrict__ bstart,
                                                    unsigned* __restrict__ row_ptr,
                                                    int* __restrict__ sorted_all)
{
    __shared__ unsigned hist[1 << BSHIFT];   // 8KB: counts -> absolute cursors
    __shared__ unsigned wsum[4];
    int c = blockIdx.x;
    int dbase = c << BSHIFT;
    for (int i = threadIdx.x; i < (1 << BSHIFT); i += 256) hist[i] = 0;
    __syncthreads();
    const unsigned* eb = ebuf + (unsigned)c * BCAP;
    unsigned n = bcnt[c];
    for (unsigned e = threadIdx.x; e < n; e += 256)
        atomicAdd(&hist[eb[e] >> 17], 1u);
    __syncthreads();
    int base8 = threadIdx.x * 8;
    unsigned loc[8], s = 0;
#pragma unroll
    for (int i = 0; i < 8; ++i) { loc[i] = s; s += hist[base8 + i]; }
    int lane = threadIdx.x & 63, wv = threadIdx.x >> 6;
    unsigned sc = s;
    for (int off = 1; off < 64; off <<= 1) {
        unsigned t = __shfl_up(sc, off, 64);
        if (lane >= off) sc += t;
    }
    if (lane == 63) wsum[wv] = sc;
    __syncthreads();
    unsigned woff = 0;
    for (int w = 0; w < wv; ++w) woff += wsum[w];
    unsigned tbase = bstart[c] + woff + sc - s;   // absolute exclusive prefix
#pragma unroll
    for (int i = 0; i < 8; ++i) {
        int dd = dbase + base8 + i;
        unsigned p = tbase + loc[i];
        if (dd < N_ALL) row_ptr[dd] = p;
        hist[base8 + i] = p;                      // becomes the fill cursor
    }
    __syncthreads();
    for (unsigned e = threadIdx.x; e < n; e += 256) {
        unsigned v = eb[e];
        unsigned pos = atomicAdd(&hist[v >> 17], 1u);
        sorted_all[pos] = (int)(v & 0x1FFFFu);
    }
}

// ---------------- all weights: transpose + bf16 + XOR-swizzle ----------------
__global__ __launch_bounds__(256) void wprep_all_kernel(
    const float* __restrict__ W1l, const float* __restrict__ W1r,
    const float* __restrict__ W2l, const float* __restrict__ W2r,
    const float* __restrict__ W3l, const float* __restrict__ W3r,
    const float* __restrict__ Wlin, unsigned short* __restrict__ wtbase)
{
    int e = blockIdx.x * 256 + threadIdx.x;
    if (e >= 6 * 16384 + 8192) return;
    const float* srcs[7] = { W1l, W1r, W2l, W2r, W3l, W3r, Wlin };
    int m = e >> 14;
    int local = (m < 6) ? (e & 16383) : (e - 98304);
    int N = (m < 6) ? 128 : 64;
    int k = local / N, col = local - k * N;
    unsigned short* dst = wtbase + ((m < 6) ? m * 16384 : 98304);
    dst[(col * 128 + k) ^ ((col & 7) << 3)] = f2bf(srcs[m][local]);
}

// ---------------- gemmTh2: fused hp-mean gather + dual GEMM -> full X2 rows ----------------
__global__ __launch_bounds__(1024) void gemmTh2_kernel(
    const float* __restrict__ X /*x_taxon f32*/,
    const unsigned* __restrict__ rp, const int* __restrict__ nbr,
    const unsigned short* __restrict__ WtA, const unsigned short* __restrict__ WtB,
    const float* __restrict__ bias, unsigned* __restrict__ X2, int M)
{
    __shared__ char sW[65536];
    __shared__ unsigned tiles[16 * 1024];
    int tid = threadIdx.x;
    ((i32x4*)sW)[tid]        = ((const i32x4*)WtA)[tid];
    ((i32x4*)sW)[tid + 1024] = ((const i32x4*)WtA)[tid + 1024];
    ((i32x4*)sW)[tid + 2048] = ((const i32x4*)WtB)[tid];
    ((i32x4*)sW)[tid + 3072] = ((const i32x4*)WtB)[tid + 1024];

    int wave = tid >> 6, lane = tid & 63;
    int ln = lane & 15, g = lane >> 4;
    int rbase = blockIdx.x * 256 + wave * 16;
    unsigned* tile = tiles + wave * 1024;

    // gather phase: mean of hp neighbors for the wave's 16 rows (deg~2)
    for (int i = 0; i < 16; ++i) {
        int r = rbase + i;
        float a0 = 0.f, a1 = 0.f;
        if (r < M) {
            unsigned beg = rp[r], end = rp[r + 1];
            unsigned u = beg;
            for (; u + 2 <= end; u += 2) {
                float2 A = ((const float2*)X)[(size_t)nbr[u] * 64 + lane];
                float2 B = ((const float2*)X)[(size_t)nbr[u + 1] * 64 + lane];
                a0 += A.x + B.x; a1 += A.y + B.y;
            }
            if (u < end) {
                float2 A = ((const float2*)X)[(size_t)nbr[u] * 64 + lane];
                a0 += A.x; a1 += A.y;
            }
            unsigned cdeg = end - beg;
            float inv = 1.f / (float)(cdeg ? cdeg : 1u);
            a0 *= inv; a1 *= inv;
        }
        tile[i * 64 + (lane ^ ((i & 7) << 2))] = packbf(a0, a1);
    }
    __syncthreads();

    // GEMM phase
    int row = rbase + ln;
    int rl = row < M ? row : M - 1;
    int swzW = (ln & 7) << 4;
    int swz = (ln & 7) << 2;

    f32x4 acc[8];
#pragma unroll
    for (int cf = 0; cf < 8; ++cf) acc[cf] = ((const f32x4*)bias)[cf * 4 + g];

    const f32x4* xr = (const f32x4*)(X + (size_t)rl * 128);
    unsigned* orow = X2 + (size_t)row * 128;
    i32x4 xpk[4];
#pragma unroll
    for (int ks = 0; ks < 4; ++ks) {
        Frag mf; mf.i = *(const i32x4*)&tile[ln * 64 + ((ks * 16 + g * 4) ^ swz)];
        f32x4 fa = xr[ks * 8 + g * 2], fb = xr[ks * 8 + g * 2 + 1];
        Frag xf;
        i32x4 t = { (int)packbf(fa.x, fa.y), (int)packbf(fa.z, fa.w),
                    (int)packbf(fb.x, fb.y), (int)packbf(fb.z, fb.w) };
        xf.i = t; xpk[ks] = t;
#pragma unroll
        for (int cf = 0; cf < 8; ++cf) {
            int off = (((cf * 16 + ln) << 8) + (ks << 6) + (g << 4)) ^ swzW;
            Frag wa; wa.i = *(const i32x4*)(sW + off);
            Frag wb; wb.i = *(const i32x4*)(sW + 32768 + off);
            acc[cf] = __builtin_amdgcn_mfma_f32_16x16x32_bf16(wa.v, mf.v, acc[cf], 0, 0, 0);
            acc[cf] = __builtin_amdgcn_mfma_f32_16x16x32_bf16(wb.v, xf.v, acc[cf], 0, 0, 0);
        }
    }

    if (row < M) {
#pragma unroll
        for (int ks = 0; ks < 4; ++ks) {
            int p0 = 16 * ks + 4 * g;
            orow[(p0 + 0) * 2] = (unsigned)xpk[ks][0];
            orow[(p0 + 1) * 2] = (unsigned)xpk[ks][1];
            orow[(p0 + 2) * 2] = (unsigned)xpk[ks][2];
            orow[(p0 + 3) * 2] = (unsigned)xpk[ks][3];
        }
#pragma unroll
        for (int cf = 0; cf < 8; ++cf) {
            int p = cf * 8 + g * 2;
            orow[p * 2 + 1]       = packbf(fmaxf(acc[cf][0], 0.f), fmaxf(acc[cf][1], 0.f));
            orow[(p + 1) * 2 + 1] = packbf(fmaxf(acc[cf][2], 0.f), fmaxf(acc[cf][3], 0.f));
        }
    }
}

// ---------------- merged rh gather: chunk-8 MLP, XCD-swizzled ----------------
__global__ __launch_bounds__(256) void aggMean2_kernel(
    const unsigned* __restrict__ X2, const unsigned* __restrict__ rp,
    const int* __restrict__ nbr,
    unsigned* __restrict__ meanXrh, unsigned* __restrict__ meanH)
{
    int wave = threadIdx.x >> 6, lane = threadIdx.x & 63;
    int bid = (blockIdx.x & 7) * 6250 + (blockIdx.x >> 3);   // grid = 50000
    int r = bid * 4 + wave;
    unsigned beg = rp[r], end = rp[r + 1];
    float a0 = 0.f, a1 = 0.f, a2 = 0.f, a3 = 0.f;
    unsigned u = beg;
    for (; u + 8 <= end; u += 8) {
        int j[8];
#pragma unroll
        for (int k = 0; k < 8; ++k) j[k] = nbr[u + k];
        u32x2 A[8];
#pragma unroll
        for (int k = 0; k < 8; ++k)
            A[k] = *(const u32x2*)(X2 + (size_t)j[k] * 128 + lane * 2);
#pragma unroll
        for (int k = 0; k < 8; ++k) {
            a0 += bflo(A[k].x); a1 += bfhi(A[k].x);
            a2 += bflo(A[k].y); a3 += bfhi(A[k].y);
        }
    }
    for (; u + 2 <= end; u += 2) {
        int j0 = nbr[u], j1 = nbr[u + 1];
        u32x2 A = *(const u32x2*)(X2 + (size_t)j0 * 128 + lane * 2);
        u32x2 B = *(const u32x2*)(X2 + (size_t)j1 * 128 + lane * 2);
        a0 += bflo(A.x) + bflo(B.x); a1 += bfhi(A.x) + bfhi(B.x);
        a2 += bflo(A.y) + bflo(B.y); a3 += bfhi(A.y) + bfhi(B.y);
    }
    if (u < end) {
        u32x2 A = *(const u32x2*)(X2 + (size_t)nbr[u] * 128 + lane * 2);
        a0 += bflo(A.x); a1 += bfhi(A.x); a2 += bflo(A.y); a3 += bfhi(A.y);
    }
    unsigned c = end - beg;
    float inv = 1.f / (float)(c ? c : 1u);
    meanXrh[(size_t)r * 64 + lane] = packbf(a0 * inv, a1 * inv);
    meanH[(size_t)r * 64 + lane]   = packbf(a2 * inv, a3 * inv);
}

// ---------------- megaTail: sotu_h (LDS tiles) -> h2 (in-place) -> out ----------------
__global__ __launch_bounds__(1024) void megaTail_kernel(
    const unsigned* __restrict__ meanXrh, const float* __restrict__ xs,
    const unsigned* __restrict__ meanH,
    const unsigned short* __restrict__ Wt2l, const unsigned short* __restrict__ Wt2r,
    const unsigned short* __restrict__ Wt3l, const unsigned short* __restrict__ Wt3r,
    const unsigned short* __restrict__ Wtlin,
    const float* __restrict__ b2, const float* __restrict__ b3,
    const float* __restrict__ blin, float* __restrict__ out, int M)
{
    __shared__ char sW[65536];
    __shared__ unsigned tiles[16 * 1024];
    int tid = threadIdx.x;
    int wave = tid >> 6, lane = tid & 63;
    int ln = lane & 15, g = lane >> 4;
    int row = blockIdx.x * 256 + wave * 16 + ln;
    int rl = row < M ? row : M - 1;
    int swzW = (ln & 7) << 4;
    int swz = (ln & 7) << 2;
    unsigned* tile = tiles + wave * 1024;

    i32x4 w3pre[4], wlpre;
    w3pre[0] = ((const i32x4*)Wt3l)[tid];
    w3pre[1] = ((const i32x4*)Wt3l)[tid + 1024];
    w3pre[2] = ((const i32x4*)Wt3r)[tid];
    w3pre[3] = ((const i32x4*)Wt3r)[tid + 1024];
    wlpre    = ((const i32x4*)Wtlin)[tid];

    ((i32x4*)sW)[tid]        = ((const i32x4*)Wt2l)[tid];
    ((i32x4*)sW)[tid + 1024] = ((const i32x4*)Wt2l)[tid + 1024];
    ((i32x4*)sW)[tid + 2048] = ((const i32x4*)Wt2r)[tid];
    ((i32x4*)sW)[tid + 3072] = ((const i32x4*)Wt2r)[tid + 1024];
    __syncthreads();   // B1

    // phase A: sotu_h = relu(meanXrh@W2l + x_sotu@W2r + b2) -> tile
    {
        f32x4 acc[8];
#pragma unroll
        for (int cf = 0; cf < 8; ++cf) acc[cf] = ((const f32x4*)b2)[cf * 4 + g];
        const i32x4* a1r = (const i32x4*)(meanXrh + (size_t)rl * 64);
        const f32x4* xr = (const f32x4*)(xs + (size_t)rl * 128);
#pragma unroll
        for (int ks = 0; ks < 4; ++ks) {
            Frag mf; mf.i = a1r[ks * 4 + g];
            f32x4 fa = xr[ks * 8 + g * 2], fb = xr[ks * 8 + g * 2 + 1];
            Frag xf;
            i32x4 t = { (int)packbf(fa.x, fa.y), (int)packbf(fa.z, fa.w),
                        (int)packbf(fb.x, fb.y), (int)packbf(fb.z, fb.w) };
            xf.i = t;
#pragma unroll
            for (int cf = 0; cf < 8; ++cf) {
                int off = (((cf * 16 + ln) << 8) + (ks << 6) + (g << 4)) ^ swzW;
                Frag wa; wa.i = *(const i32x4*)(sW + off);
                Frag wb; wb.i = *(const i32x4*)(sW + 32768 + off);
                acc[cf] = __builtin_amdgcn_mfma_f32_16x16x32_bf16(wa.v, mf.v, acc[cf], 0, 0, 0);
                acc[cf] = __builtin_amdgcn_mfma_f32_16x16x32_bf16(wb.v, xf.v, acc[cf], 0, 0, 0);
            }
        }
#pragma unroll
        for (int cf = 0; cf < 8; ++cf) {
            u32x2 o;
            o.x = packbf(fmaxf(acc[cf][0], 0.f), fmaxf(acc[cf][1], 0.f));
            o.y = packbf(fmaxf(acc[cf][2], 0.f), fmaxf(acc[cf][3], 0.f));
            *(u32x2*)&tile[ln * 64 + ((cf * 8 + g * 2) ^ swz)] = o;
        }
    }

    i32x4 mh[4];
    {
        const i32x4* hr = (const i32x4*)(meanH + (size_t)rl * 64);
#pragma unroll
        for (int ks = 0; ks < 4; ++ks) mh[ks] = hr[ks * 4 + g];
    }
    __syncthreads();   // B2
    ((i32x4*)sW)[tid]        = w3pre[0];
    ((i32x4*)sW)[tid + 1024] = w3pre[1];
    ((i32x4*)sW)[tid + 2048] = w3pre[2];
    ((i32x4*)sW)[tid + 3072] = w3pre[3];
    __syncthreads();   // B3

    // phase B: h2 = relu(meanH@W3l + sotu_h@W3r + b3) -> tile (in place)
    {
        f32x4 acc2[8];
#pragma unroll
        for (int cf = 0; cf < 8; ++cf) acc2[cf] = ((const f32x4*)b3)[cf * 4 + g];
#pragma unroll
        for (int ks = 0; ks < 4; ++ks) {
            Frag mf; mf.i = mh[ks];
            Frag sf; sf.i = *(const i32x4*)&tile[ln * 64 + ((ks * 16 + g * 4) ^ swz)];
#pragma unroll
            for (int cf = 0; cf < 8; ++cf) {
                int off = (((cf * 16 + ln) << 8) + (ks << 6) + (g << 4)) ^ swzW;
                Frag wl; wl.i = *(const i32x4*)(sW + off);
                Frag wr; wr.i = *(const i32x4*)(sW + 32768 + off);
                acc2[cf] = __builtin_amdgcn_mfma_f32_16x16x32_bf16(wl.v, mf.v, acc2[cf], 0, 0, 0);
                acc2[cf] = __builtin_amdgcn_mfma_f32_16x16x32_bf16(wr.v, sf.v, acc2[cf], 0, 0, 0);
            }
        }
#pragma unroll
        for (int cf = 0; cf < 8; ++cf) {
            u32x2 o;
            o.x = packbf(fmaxf(acc2[cf][0], 0.f), fmaxf(acc2[cf][1], 0.f));
            o.y = packbf(fmaxf(acc2[cf][2], 0.f), fmaxf(acc2[cf][3], 0.f));
            *(u32x2*)&tile[ln * 64 + ((cf * 8 + g * 2) ^ swz)] = o;
        }
    }
    __syncthreads();   // B4
    ((i32x4*)sW)[tid] = wlpre;
    __syncthreads();   // B5

    // phase C: out = h2 @ Wlin + blin
    f32x4 aL[4];
#pragma unroll
    for (int cf = 0; cf < 4; ++cf) aL[cf] = ((const f32x4*)blin)[cf * 4 + g];
#pragma unroll
    for (int ks = 0; ks < 4; ++ks) {
        Frag hf; hf.i = *(const i32x4*)&tile[ln * 64 + ((ks * 16 + g * 4) ^ swz)];
#pragma unroll
        for (int cf = 0; cf < 4; ++cf) {
            int off = (((cf * 16 + ln) << 8) + (ks << 6) + (g << 4)) ^ swzW;
            Frag wf; wf.i = *(const i32x4*)(sW + off);
            aL[cf] = __builtin_amdgcn_mfma_f32_16x16x32_bf16(wf.v, hf.v, aL[cf], 0, 0, 0);
        }
    }
    if (row < M) {
        float* orow = out + (size_t)row * OUTC;
#pragma unroll
        for (int cf = 0; cf < 4; ++cf)
            *(f32x4*)(orow + cf * 16 + g * 4) = aL[cf];
    }
}

extern "C" void kernel_launch(void* const* d_in, const int* in_sizes, int n_in,
                              void* d_out, int out_size, void* d_ws, size_t ws_size,
                              hipStream_t stream)
{
    const float* x_taxon = (const float*)d_in[0];
    const float* x_sotu  = (const float*)d_in[1];
    const int* hp_src = (const int*)d_in[2];
    const int* hp_dst = (const int*)d_in[3];
    const int* rh_src = (const int*)d_in[4];
    const int* rh_dst = (const int*)d_in[5];
    const float* W1l = (const float*)d_in[6];
    const float* W1r = (const float*)d_in[7];
    const float* b1  = (const float*)d_in[8];
    const float* W2l = (const float*)d_in[9];
    const float* W2r = (const float*)d_in[10];
    const float* b2  = (const float*)d_in[11];
    const float* W3l = (const float*)d_in[12];
    const float* W3r = (const float*)d_in[13];
    const float* b3  = (const float*)d_in[14];
    const float* Wlin = (const float*)d_in[15];
    const float* blin = (const float*)d_in[16];
    float* out = (float*)d_out;

    // ---- workspace layout (bytes) ----
    char* ws = (char*)d_ws;
    unsigned* X2      = (unsigned*)(ws);                  // [100K][128] xt|taxon_h interleaved
    unsigned* meanXrh = (unsigned*)(ws + 51200000);       // [200K][64]; ebuf overlays (dead first)
    unsigned* meanH   = (unsigned*)(ws + 102400000);      // [200K][64]
    unsigned* ebuf    = (unsigned*)(ws + 51200000);       // [147*24576] u32 = 14.5MB, dead before aggMean2
    int*      sorted_all = (int*)(ws + 179200000);        // [E_ALL] 8.8MB
    unsigned* row_ptr = (unsigned*)(ws + 188000000);      // [300001]
    unsigned* bcnt    = (unsigned*)(ws + 189200128);      // [160]
    unsigned* bstart  = (unsigned*)(ws + 189200768);      // [160]
    unsigned short* wtbase = (unsigned short*)(ws + 189201408);
    unsigned short* Wt1l = wtbase;
    unsigned short* Wt1r = wtbase + 16384;
    unsigned short* Wt2l = wtbase + 32768;
    unsigned short* Wt2r = wtbase + 49152;
    unsigned short* Wt3l = wtbase + 65536;
    unsigned short* Wt3r = wtbase + 81920;
    unsigned short* Wtlin = wtbase + 98304;

    // zero bcnt only
    hipMemsetAsync(bcnt, 0, 640, stream);

    // ---- weight prep (independent) ----
    wprep_all_kernel<<<(6 * 16384 + 8192 + 255) / 256, 256, 0, stream>>>(
        W1l, W1r, W2l, W2r, W3l, W3r, Wlin, wtbase);

    // ---- unified CSR build (fixed-capacity buckets, no count pass) ----
    partition_kernel<<<(E_ALL + 4095) / 4096, 256, 0, stream>>>(
        hp_src, hp_dst, rh_src, rh_dst, bcnt, ebuf);
    scan147_kernel<<<1, 256, 0, stream>>>(bcnt, bstart, row_ptr);
    fillB_kernel<<<NBUCK, 256, 0, stream>>>(ebuf, bcnt, bstart, row_ptr, sorted_all);

    // ---- fused hp-mean + taxon_h GEMM -> full X2 rows ----
    gemmTh2_kernel<<<(N_TAXON + 255) / 256, 1024, 0, stream>>>(
        x_taxon, row_ptr, sorted_all, Wt1l, Wt1r, b1, X2, N_TAXON);

    // ---- merged rh gather: meanXrh + meanH in one walk (chunk-8) ----
    aggMean2_kernel<<<N_SOTU / 4, 256, 0, stream>>>(
        X2, row_ptr + N_TAXON, sorted_all, meanXrh, meanH);

    // ---- megaTail: sotu_h -> h2 (LDS) -> out ----
    megaTail_kernel<<<(N_SOTU + 255) / 256, 1024, 0, stream>>>(
        meanXrh, x_sotu, meanH, Wt2l, Wt2r, Wt3l, Wt3r, Wtlin, b2, b3, blin, out, N_SOTU);
}